// Round 7
// baseline (4695.918 us; speedup 1.0000x reference)
//
#include <hip/hip_runtime.h>
#include <stdint.h>

#define B_     4096
#define IN_DIM 2048
#define KCB    8192
#define DD     256
#define SS     8
#define ND     (SS*DD)   // 2048

// ---------------------------------------------------------------------------
// SGEMM (NT): C[M,N] = A[M,K] * B[N,K]^T + bias[N].  Row-major everything.
// BM=BN=128, BK=16, 256 threads, 8x8 micro-tile, 4+4 fragment mapping.
// v6 engine (PROVEN: 128 VGPR, 4 waves/SIMD, single-buffered, 2 barriers/kt).
// ---------------------------------------------------------------------------
#define BM 128
#define BN 128
#define BK 16
#define LDSP 132   // padded leading dim

__global__ __launch_bounds__(256) void sgemm_nt_bias_v6(
    const float* __restrict__ A, const float* __restrict__ Bm,
    const float* __restrict__ bias, float* __restrict__ C,
    int M, int N, int K)
{
    __shared__ float As[BK][LDSP];
    __shared__ float Bs[BK][LDSP];
    const int tid = threadIdx.x;
    const int tx  = tid & 15;       // n-group
    const int ty  = tid >> 4;       // m-group
    const int m0  = blockIdx.y * BM;
    const int n0  = blockIdx.x * BN;

    float acc[8][8];
    #pragma unroll
    for (int i = 0; i < 8; ++i)
        #pragma unroll
        for (int j = 0; j < 8; ++j) acc[i][j] = 0.f;

    for (int kt = 0; kt < K; kt += BK) {
        #pragma unroll
        for (int l = 0; l < 2; ++l) {
            int idx = tid + l * 256;          // 0..511
            int row = idx >> 2;               // 0..127
            int c4  = (idx & 3) * 4;          // 0,4,8,12
            float4 av = *(const float4*)(A  + (size_t)(m0 + row) * K + kt + c4);
            As[c4+0][row] = av.x; As[c4+1][row] = av.y;
            As[c4+2][row] = av.z; As[c4+3][row] = av.w;
            float4 bv = *(const float4*)(Bm + (size_t)(n0 + row) * K + kt + c4);
            Bs[c4+0][row] = bv.x; Bs[c4+1][row] = bv.y;
            Bs[c4+2][row] = bv.z; Bs[c4+3][row] = bv.w;
        }
        __syncthreads();
        #pragma unroll
        for (int kk = 0; kk < BK; ++kk) {
            float a[8], b[8];
            *(float4*)&a[0] = *(const float4*)&As[kk][ty*4];
            *(float4*)&a[4] = *(const float4*)&As[kk][64 + ty*4];
            *(float4*)&b[0] = *(const float4*)&Bs[kk][tx*4];
            *(float4*)&b[4] = *(const float4*)&Bs[kk][64 + tx*4];
            #pragma unroll
            for (int i = 0; i < 8; ++i)
                #pragma unroll
                for (int j = 0; j < 8; ++j) acc[i][j] += a[i] * b[j];
        }
        __syncthreads();
    }

    // epilogue: rows {ty*4+i | i<4} u {64+ty*4+(i-4)}, cols {tx*4.., 64+tx*4..}
    #pragma unroll
    for (int i = 0; i < 8; ++i) {
        const int m = m0 + ((i < 4) ? (ty*4 + i) : (64 + ty*4 + (i - 4)));
        float4 v0, v1;
        v0.x = acc[i][0] + bias[n0 + tx*4 + 0];
        v0.y = acc[i][1] + bias[n0 + tx*4 + 1];
        v0.z = acc[i][2] + bias[n0 + tx*4 + 2];
        v0.w = acc[i][3] + bias[n0 + tx*4 + 3];
        v1.x = acc[i][4] + bias[n0 + 64 + tx*4 + 0];
        v1.y = acc[i][5] + bias[n0 + 64 + tx*4 + 1];
        v1.z = acc[i][6] + bias[n0 + 64 + tx*4 + 2];
        v1.w = acc[i][7] + bias[n0 + 64 + tx*4 + 3];
        *(float4*)(C + (size_t)m * N + n0 + tx*4) = v0;
        *(float4*)(C + (size_t)m * N + n0 + 64 + tx*4) = v1;
    }
}

// ---------------------------------------------------------------------------
// z_sq[b*S+s] = fp32 sum_d z[b, s*256+d]^2.  One wave per (b,s) row.
// ---------------------------------------------------------------------------
__global__ __launch_bounds__(256) void zsq_v4(
    const float* __restrict__ Z, float* __restrict__ zsq)
{
    int gw   = (blockIdx.x * 256 + threadIdx.x) >> 6;   // row = b*8+s
    int lane = threadIdx.x & 63;
    float4 v = *(const float4*)(Z + (size_t)gw * DD + lane * 4);
    float ssum = v.x*v.x + v.y*v.y + v.z*v.z + v.w*v.w;
    #pragma unroll
    for (int off = 32; off; off >>= 1) ssum += __shfl_down(ssum, off, 64);
    if (lane == 0) zsq[gw] = ssum;
}

// ---------------------------------------------------------------------------
// async global->LDS staging helper (width 4: per-lane global addr, LDS dest
// = uniform base + lane*4).  Zero VGPR staging cost; tracked by vmcnt.
// ---------------------------------------------------------------------------
typedef __attribute__((address_space(1))) const void global_cvoid;
typedef __attribute__((address_space(3))) void lds_void;

__device__ __forceinline__ void gll4(const float* g, float* l)
{
    __builtin_amdgcn_global_load_lds((global_cvoid*)g, (lds_void*)l, 4, 0, 0);
}

// ---------------------------------------------------------------------------
// Distance + argmin v10: v6 engine + async DMA double-buffered staging.
// Model (validated v4..v9): VALU-busy time is constant ~1220us; variants
// differ only in stall.  VGPR>128 halves waves/SIMD (v4/v7/v8/v9 all 2
// waves -> 51-57% VALUBusy); register prefetch is therefore impossible.
// global_load_lds stages with ZERO register cost: per K-step each wave
// issues 16 width-4 DMA loads into buffer q (transposed content identical
// to v6 via per-lane source addresses), then waits vmcnt(16) = only the
// PREVIOUS tile's loads (landed under the 2100-cyc FMA phase) -> loads
// stay in flight across barriers, never drained to 0 mid-loop (T4).
// Two raw barriers/step: #1 after own-vmcnt => all waves' tile-t data
// landed; #2 after compute => nobody still reads buf q when t+2's DMA
// targets it.  Empty "memory" asms pin ds_reads inside the barrier pair.
// Fragment reads + FMA order unchanged from v6 -> bit-identical codes.
// grid = (K/1024, B/128, S), block 256.
// ---------------------------------------------------------------------------
__global__ __launch_bounds__(256) void dist_argmin_v10(
    const float* __restrict__ Z,    // [B, 2048]
    const float* __restrict__ CB,   // [S, K, D]
    const float* __restrict__ zsq,  // [B*S]
    unsigned long long* __restrict__ minp)  // [B*S][8]
{
    __shared__ float As[2][BK][LDSP];
    __shared__ float Bs[2][BK][LDSP];
    const int tid  = threadIdx.x;
    const int tx   = tid & 15;
    const int ty   = tid >> 4;
    const int wid  = tid >> 6;     // wave 0..3
    const int lane = tid & 63;
    const int s     = blockIdx.z;
    const int m0    = blockIdx.y * 128;
    const int nbase = blockIdx.x * 1024;
    const float* Az = Z  + (size_t)s * DD;        // lda = ND
    const float* Bc = CB + (size_t)s * KCB * DD;  // row stride = DD

    float Zr[8];
    #pragma unroll
    for (int i = 0; i < 8; ++i) {
        const int r = (i < 4) ? (ty*4 + i) : (64 + ty*4 + (i - 4));
        Zr[i] = zsq[(size_t)(m0 + r) * SS + s];
    }

    unsigned long long lmin[8];
    #pragma unroll
    for (int i = 0; i < 8; ++i) lmin[i] = ~0ull;

    // per-lane global row base pointers (fixed all kernel)
    const float* ArowL = Az + (size_t)(m0 + lane) * ND;        // A rows 0..63
    const float* ArowH = Az + (size_t)(m0 + 64 + lane) * ND;   // A rows 64..127
    const float* BrowL = Bc + (size_t)lane * DD;               // B rows n00+0..63   (+bOff)
    const float* BrowH = Bc + (size_t)(64 + lane) * DD;        // B rows n00+64..127 (+bOff)

    // stage tile t (ntS = t>>4, ktS = (t&15)*BK) into buffer b:
    // 16 DMA loads per wave; wave w covers LDS columns c = w*4..w*4+3.
    // content: As[b][c][row] = A[m0+row][ktS+c], Bs[b][c][row] = B[n00+row][ktS+c]
    #define STAGE_(t_, b_) do {                                              \
        const int ntS_ = (t_) >> 4;                                          \
        const int ktS_ = ((t_) & 15) * BK;                                   \
        const size_t bOff_ = (size_t)(nbase + ntS_ * 128) * DD + ktS_;       \
        _Pragma("unroll")                                                    \
        for (int sl_ = 0; sl_ < 4; ++sl_) {                                  \
            const int c_ = (wid << 2) + sl_;                                 \
            gll4(ArowL + ktS_ + c_,  &As[b_][c_][0]);                        \
            gll4(ArowH + ktS_ + c_,  &As[b_][c_][64]);                       \
            gll4(BrowL + bOff_ + c_, &Bs[b_][c_][0]);                        \
            gll4(BrowH + bOff_ + c_, &Bs[b_][c_][64]);                       \
        }                                                                    \
    } while (0)

    // prologue: stage tile 0 into buffer 0 (latency exposed once per block)
    STAGE_(0, 0);

    for (int nt = 0; nt < 8; ++nt) {
        float acc[8][8];
        #pragma unroll
        for (int i = 0; i < 8; ++i)
            #pragma unroll
            for (int j = 0; j < 8; ++j) acc[i][j] = 0.f;

        for (int kt16 = 0; kt16 < 16; ++kt16) {
            const int p = kt16 & 1;            // nt*16 is even -> p = kt16&1
            const int tn = nt * 16 + kt16 + 1; // next stage index
            if (tn < 128) {
                STAGE_(tn, p ^ 1);
                asm volatile("s_waitcnt vmcnt(16)" ::: "memory"); // tile t landed (mine)
            } else {
                asm volatile("s_waitcnt vmcnt(0)" ::: "memory");
            }
            __builtin_amdgcn_s_barrier();          // => everyone's tile t landed
            asm volatile("" ::: "memory");         // pin ds_reads below barrier

            const float (*Al)[LDSP] = As[p];
            const float (*Bl)[LDSP] = Bs[p];
            #pragma unroll
            for (int kk = 0; kk < BK; ++kk) {
                float a[8], b[8];
                *(float4*)&a[0] = *(const float4*)&Al[kk][ty*4];
                *(float4*)&a[4] = *(const float4*)&Al[kk][64 + ty*4];
                *(float4*)&b[0] = *(const float4*)&Bl[kk][tx*4];
                *(float4*)&b[4] = *(const float4*)&Bl[kk][64 + tx*4];
                #pragma unroll
                for (int i = 0; i < 8; ++i)
                    #pragma unroll
                    for (int j = 0; j < 8; ++j) acc[i][j] += a[i] * b[j];
            }

            asm volatile("" ::: "memory");         // pin ds_reads above barrier
            __builtin_amdgcn_s_barrier();          // buf p free for stage t+2
        }

        // epilogue: quantized score (fp32 round-half-even, same as np),
        // pack, running min.  j<4 -> n=tx*4+j ; j>=4 -> n=64+tx*4+(j-4)
        const int n00 = nbase + nt * 128;
        #pragma unroll
        for (int i = 0; i < 8; ++i) {
            #pragma unroll
            for (int j = 0; j < 8; ++j) {
                const int n = n00 + ((j < 4) ? (tx*4 + j) : (64 + tx*4 + (j - 4)));
                const float d = Zr[i] - 2.f * acc[i][j];   // x2 exact; ties collapse here
                unsigned u = __float_as_uint(d);
                u = (d < 0.f) ? ~u : (u | 0x80000000u);
                const unsigned long long pk = ((unsigned long long)u << 32) | (unsigned)n;
                if (pk < lmin[i]) lmin[i] = pk;
            }
        }
    }
    #undef STAGE_

    // min across the 16 tx lanes (lanes with equal ty sit in the same wave)
    #pragma unroll
    for (int i = 0; i < 8; ++i) {
        unsigned long long v = lmin[i];
        #pragma unroll
        for (int off = 1; off < 16; off <<= 1) {
            unsigned long long o = __shfl_xor(v, off, 64);
            if (o < v) v = o;
        }
        lmin[i] = v;
    }
    if (tx == 0) {
        #pragma unroll
        for (int i = 0; i < 8; ++i) {
            const int r = (i < 4) ? (ty*4 + i) : (64 + ty*4 + (i - 4));
            minp[((size_t)(m0 + r) * SS + s) * 8 + blockIdx.x] = lmin[i];
        }
    }
}

// ---------------------------------------------------------------------------
// Merge the 8 per-block minima per row -> final code.
// ---------------------------------------------------------------------------
__global__ __launch_bounds__(256) void reduce_min_v4(
    const unsigned long long* __restrict__ minp,   // [B*S][8]
    int* __restrict__ kfinal)
{
    int row = blockIdx.x * 256 + threadIdx.x;
    if (row >= B_ * SS) return;
    unsigned long long b1 = ~0ull;
    #pragma unroll
    for (int j = 0; j < 8; ++j) {
        unsigned long long v = minp[(size_t)row * 8 + j];
        if (v < b1) b1 = v;
    }
    kfinal[row] = (int)(b1 & 0xFFFFFFFFull);
}

// ---------------------------------------------------------------------------
// Gather quantized vectors, emit codes (as float), histogram counts.
// ---------------------------------------------------------------------------
__global__ __launch_bounds__(256) void gather_v4(
    const float* __restrict__ CB,
    const int* __restrict__ kfinal,
    float* __restrict__ quant,   // [B, 2048]
    float* __restrict__ codes,   // [B, S]
    unsigned* __restrict__ counts) // [S, K]
{
    const int b = blockIdx.x;
    const int tid = threadIdx.x;
    __shared__ int ks[SS];
    if (tid < SS) {
        int k = kfinal[(size_t)b * SS + tid];
        ks[tid] = k;
        codes[(size_t)b * SS + tid] = (float)k;
        atomicAdd(&counts[(size_t)tid * KCB + k], 1u);
    }
    __syncthreads();
    #pragma unroll
    for (int l = 0; l < 2; ++l) {
        int f  = tid + l * 256;
        int s  = f >> 6;
        int d4 = f & 63;
        float4 v = *(const float4*)(CB + ((size_t)s * KCB + ks[s]) * DD + d4 * 4);
        *(float4*)(quant + (size_t)b * ND + s * DD + d4 * 4) = v;
    }
}

// ---------------------------------------------------------------------------
__global__ __launch_bounds__(256) void perp_v4(
    const unsigned* __restrict__ counts, float* __restrict__ out)
{
    __shared__ float red[256];
    const int tid = threadIdx.x;
    const float inv = 1.0f / (float)B_;
    float sumP = 0.f;
    for (int s = 0; s < SS; ++s) {
        float h = 0.f;
        for (int k = tid; k < KCB; k += 256) {
            float p = (float)counts[(size_t)s * KCB + k] * inv;
            h += p * logf(p + 1e-10f);
        }
        red[tid] = h;
        __syncthreads();
        for (int w = 128; w; w >>= 1) {
            if (tid < w) red[tid] += red[tid + w];
            __syncthreads();
        }
        if (tid == 0) sumP += expf(-red[0]);
        __syncthreads();
    }
    if (tid == 0) out[0] = sumP / (float)SS;
}

// ---------------------------------------------------------------------------
extern "C" void kernel_launch(void* const* d_in, const int* in_sizes, int n_in,
                              void* d_out, int out_size, void* d_ws, size_t ws_size,
                              hipStream_t stream)
{
    const float* x     = (const float*)d_in[0];
    const float* enc_w = (const float*)d_in[1];
    const float* enc_b = (const float*)d_in[2];
    const float* cb    = (const float*)d_in[3];
    const float* dec_w = (const float*)d_in[4];
    const float* dec_b = (const float*)d_in[5];

    float* out0 = (float*)d_out;                       // x_recon (holds z temporarily)
    float* out1 = out0 + (size_t)B_ * ND;              // quantized_flat
    float* out2 = out1 + (size_t)B_ * ND;              // codes (as float)
    float* out3 = out2 + (size_t)B_ * SS;              // avg_perplexity scalar

    // workspace layout:
    //   minp   [B*S][8] u64 : 2 MB   (fully overwritten each call)
    //   counts [S*K] u32    : 256 KB (memset 0)
    //   kfinal [B*S] i32    : 128 KB
    //   zsq    [B*S] f32    : 128 KB
    char* wsb = (char*)d_ws;
    unsigned long long* minp = (unsigned long long*)wsb;
    size_t off = (size_t)B_ * SS * 8 * sizeof(unsigned long long);
    unsigned* counts = (unsigned*)(wsb + off);  off += (size_t)SS * KCB * 4;
    int*      kfinal = (int*)(wsb + off);       off += (size_t)B_ * SS * 4;
    float*    zsq    = (float*)(wsb + off);

    hipMemsetAsync(counts, 0, (size_t)SS * KCB * 4, stream);

    // 1. encoder GEMM: z -> out0 (temp)
    dim3 g1(ND / BN, B_ / BM);   // (16, 32)
    sgemm_nt_bias_v6<<<g1, 256, 0, stream>>>(x, enc_w, enc_b, out0, B_, ND, IN_DIM);

    // 2. per-(b,s) z_sq (the constant that drives the fp32 quantization)
    zsq_v4<<<(B_ * SS) / 4, 256, 0, stream>>>(out0, zsq);

    // 3. fused distance + argmin with reference-matching fp32 rounding
    dim3 g2(KCB / 1024, B_ / 128, SS);   // (8, 32, 8)
    dist_argmin_v10<<<g2, 256, 0, stream>>>(out0, cb, zsq, minp);

    // 4. merge per-block minima -> codes
    reduce_min_v4<<<(B_ * SS + 255) / 256, 256, 0, stream>>>(minp, kfinal);

    // 5. gather + codes + histogram
    gather_v4<<<B_, 256, 0, stream>>>(cb, kfinal, out1, out2, counts);

    // 6. decoder GEMM: x_recon -> out0 (overwrites z)
    sgemm_nt_bias_v6<<<g1, 256, 0, stream>>>(out1, dec_w, dec_b, out0, B_, IN_DIM, ND);

    // 7. perplexity scalar
    perp_v4<<<1, 256, 0, stream>>>(counts, out3);
}

// Round 8
// 4191.475 us; speedup vs baseline: 1.1203x; 1.1203x over previous
//
#include <hip/hip_runtime.h>
#include <stdint.h>

#define B_     4096
#define IN_DIM 2048
#define KCB    8192
#define DD     256
#define SS     8
#define ND     (SS*DD)   // 2048

// ---------------------------------------------------------------------------
// SGEMM (NT): C[M,N] = A[M,K] * B[N,K]^T + bias[N].  Row-major everything.
// BM=BN=128, BK=16, 256 threads, 8x8 micro-tile, 4+4 fragment mapping.
// v6 engine (PROVEN best: 128 VGPR, 4 waves/SIMD, single-buffered).
// ---------------------------------------------------------------------------
#define BM 128
#define BN 128
#define BK 16
#define LDSP 132   // padded leading dim

__global__ __launch_bounds__(256) void sgemm_nt_bias_v6(
    const float* __restrict__ A, const float* __restrict__ Bm,
    const float* __restrict__ bias, float* __restrict__ C,
    int M, int N, int K)
{
    __shared__ float As[BK][LDSP];
    __shared__ float Bs[BK][LDSP];
    const int tid = threadIdx.x;
    const int tx  = tid & 15;       // n-group
    const int ty  = tid >> 4;       // m-group
    const int m0  = blockIdx.y * BM;
    const int n0  = blockIdx.x * BN;

    float acc[8][8];
    #pragma unroll
    for (int i = 0; i < 8; ++i)
        #pragma unroll
        for (int j = 0; j < 8; ++j) acc[i][j] = 0.f;

    for (int kt = 0; kt < K; kt += BK) {
        #pragma unroll
        for (int l = 0; l < 2; ++l) {
            int idx = tid + l * 256;          // 0..511
            int row = idx >> 2;               // 0..127
            int c4  = (idx & 3) * 4;          // 0,4,8,12
            float4 av = *(const float4*)(A  + (size_t)(m0 + row) * K + kt + c4);
            As[c4+0][row] = av.x; As[c4+1][row] = av.y;
            As[c4+2][row] = av.z; As[c4+3][row] = av.w;
            float4 bv = *(const float4*)(Bm + (size_t)(n0 + row) * K + kt + c4);
            Bs[c4+0][row] = bv.x; Bs[c4+1][row] = bv.y;
            Bs[c4+2][row] = bv.z; Bs[c4+3][row] = bv.w;
        }
        __syncthreads();
        #pragma unroll
        for (int kk = 0; kk < BK; ++kk) {
            float a[8], b[8];
            *(float4*)&a[0] = *(const float4*)&As[kk][ty*4];
            *(float4*)&a[4] = *(const float4*)&As[kk][64 + ty*4];
            *(float4*)&b[0] = *(const float4*)&Bs[kk][tx*4];
            *(float4*)&b[4] = *(const float4*)&Bs[kk][64 + tx*4];
            #pragma unroll
            for (int i = 0; i < 8; ++i)
                #pragma unroll
                for (int j = 0; j < 8; ++j) acc[i][j] += a[i] * b[j];
        }
        __syncthreads();
    }

    // epilogue: rows {ty*4+i | i<4} u {64+ty*4+(i-4)}, cols {tx*4.., 64+tx*4..}
    #pragma unroll
    for (int i = 0; i < 8; ++i) {
        const int m = m0 + ((i < 4) ? (ty*4 + i) : (64 + ty*4 + (i - 4)));
        float4 v0, v1;
        v0.x = acc[i][0] + bias[n0 + tx*4 + 0];
        v0.y = acc[i][1] + bias[n0 + tx*4 + 1];
        v0.z = acc[i][2] + bias[n0 + tx*4 + 2];
        v0.w = acc[i][3] + bias[n0 + tx*4 + 3];
        v1.x = acc[i][4] + bias[n0 + 64 + tx*4 + 0];
        v1.y = acc[i][5] + bias[n0 + 64 + tx*4 + 1];
        v1.z = acc[i][6] + bias[n0 + 64 + tx*4 + 2];
        v1.w = acc[i][7] + bias[n0 + 64 + tx*4 + 3];
        *(float4*)(C + (size_t)m * N + n0 + tx*4) = v0;
        *(float4*)(C + (size_t)m * N + n0 + 64 + tx*4) = v1;
    }
}

// ---------------------------------------------------------------------------
// z_sq[b*S+s] = fp32 sum_d z[b, s*256+d]^2.  One wave per (b,s) row.
// ---------------------------------------------------------------------------
__global__ __launch_bounds__(256) void zsq_v4(
    const float* __restrict__ Z, float* __restrict__ zsq)
{
    int gw   = (blockIdx.x * 256 + threadIdx.x) >> 6;   // row = b*8+s
    int lane = threadIdx.x & 63;
    float4 v = *(const float4*)(Z + (size_t)gw * DD + lane * 4);
    float ssum = v.x*v.x + v.y*v.y + v.z*v.z + v.w*v.w;
    #pragma unroll
    for (int off = 32; off; off >>= 1) ssum += __shfl_down(ssum, off, 64);
    if (lane == 0) zsq[gw] = ssum;
}

// ---------------------------------------------------------------------------
// Distance + argmin v11: scalar-A engine.
// Model (fits v4-v10): the shared LDS read pipe binds v6 at 67% VALU
// (16 waves x 4 b128 x 12cyc = 768 > VALU 512 per kk-round).  Fix: make
// rows WAVE-UNIFORM (wave w owns rows 32w..32w+31; lanes own 2 columns
// each).  A-fragments become wave-uniform -> s_load (SMEM pipe, parallel);
// B-fragment = 1 ds_read_b64/kk (2-way bank = free).  New LDS demand 128
// cyc/round << VALU 512 -> VALU-bound floor ~874us FMA.
// acc[32]x2 = 64 VGPR (same); staging = B only (v6's B pattern verbatim).
// Accumulation per (row,col): kt asc, kk asc, one fmac -> bit-identical
// scores; argmin tie-break = lowest n via score-butterfly + ballot.
// grid = (K/1024, B/128, S), block 256.
// ---------------------------------------------------------------------------
__global__ __launch_bounds__(256) void dist_argmin_v11(
    const float* __restrict__ Z,    // [B, 2048]
    const float* __restrict__ CB,   // [S, K, D]
    const float* __restrict__ zsq,  // [B*S]
    unsigned long long* __restrict__ minp)  // [B*S][8]
{
    __shared__ float Bs[BK][LDSP];   // B-tile only: 16 x 132
    const int tid  = threadIdx.x;
    const int lane = tid & 63;
    const int wid  = __builtin_amdgcn_readfirstlane(tid >> 6);   // 0..3, scalar
    const int s     = blockIdx.z;
    const int m0    = blockIdx.y * 128;
    const int nbase = blockIdx.x * 1024;
    const float* Az = Z  + (size_t)s * DD;        // lda = ND
    const float* Bc = CB + (size_t)s * KCB * DD;  // row stride = DD

    // wave-uniform A base: rows m0+32*wid .. +31 (all scalar arithmetic)
    const float* Aw = Az + (size_t)(m0 + wid * 32) * ND;

    unsigned long long lrow = ~0ull;   // lane r (<32) holds running min of row r

    for (int nt = 0; nt < 8; ++nt) {
        const int n00 = nbase + nt * 128;

        float accx[32], accy[32];      // cols lane*2, lane*2+1
        #pragma unroll
        for (int r = 0; r < 32; ++r) { accx[r] = 0.f; accy[r] = 0.f; }

        for (int kt = 0; kt < DD; kt += BK) {
            // stage B tile (v6's B pattern: coalesced float4, 2/thread)
            #pragma unroll
            for (int l = 0; l < 2; ++l) {
                int idx = tid + l * 256;
                int row = idx >> 2;               // 0..127
                int c4  = (idx & 3) * 4;
                float4 bv = *(const float4*)(Bc + (size_t)(n00 + row) * DD + kt + c4);
                Bs[c4+0][row] = bv.x; Bs[c4+1][row] = bv.y;
                Bs[c4+2][row] = bv.z; Bs[c4+3][row] = bv.w;
            }
            __syncthreads();

            #pragma unroll
            for (int kk4 = 0; kk4 < 4; ++kk4) {
                // b-fragments for 4 consecutive kk (1 ds_read_b64 each)
                const float2 b0 = *(const float2*)&Bs[kk4*4+0][lane*2];
                const float2 b1 = *(const float2*)&Bs[kk4*4+1][lane*2];
                const float2 b2 = *(const float2*)&Bs[kk4*4+2][lane*2];
                const float2 b3 = *(const float2*)&Bs[kk4*4+3][lane*2];
                #pragma unroll
                for (int rg = 0; rg < 4; ++rg) {
                    #pragma unroll
                    for (int r8 = 0; r8 < 8; ++r8) {
                        const int r = rg*8 + r8;
                        // wave-uniform address -> s_load_dwordx4
                        const float4 a4 = *(const float4*)(Aw + (size_t)r * ND + kt + kk4*4);
                        accx[r] += a4.x * b0.x;  accy[r] += a4.x * b0.y;
                        accx[r] += a4.y * b1.x;  accy[r] += a4.y * b1.y;
                        accx[r] += a4.z * b2.x;  accy[r] += a4.z * b2.y;
                        accx[r] += a4.w * b3.x;  accy[r] += a4.w * b3.y;
                    }
                }
            }
            __syncthreads();
        }

        // epilogue: per row, mono-score min across 128 cols + lowest-n
        // tie-break (identical semantics to the u64-pack scheme).
        #pragma unroll
        for (int r = 0; r < 32; ++r) {
            const float szr = zsq[(size_t)(m0 + wid*32 + r) * SS + s];  // scalar
            const float d0 = szr - 2.f * accx[r];   // x2 exact; fp32 ties collapse
            const float d1 = szr - 2.f * accy[r];
            unsigned u0 = __float_as_uint(d0); u0 = (d0 < 0.f) ? ~u0 : (u0 | 0x80000000u);
            unsigned u1 = __float_as_uint(d1); u1 = (d1 < 0.f) ? ~u1 : (u1 | 0x80000000u);
            unsigned lo = u0 < u1 ? u0 : u1;
            #pragma unroll
            for (int off = 1; off < 64; off <<= 1) {
                unsigned o = __shfl_xor(lo, off, 64);
                lo = (o < lo) ? o : lo;
            }
            // lo = winning mono-score (uniform).  Lowest n among matches:
            const unsigned long long mm0 = __ballot(u0 == lo);
            const unsigned long long mm1 = __ballot(u1 == lo);
            int nwin = 0x7FFFFFFF;
            if (mm0) nwin = n00 + 2 * (__ffsll((unsigned long long)mm0) - 1);
            if (mm1) {
                const int n1 = n00 + 2 * (__ffsll((unsigned long long)mm1) - 1) + 1;
                if (n1 < nwin) nwin = n1;
            }
            const unsigned long long cand =
                ((unsigned long long)lo << 32) | (unsigned)nwin;
            if (lane == r && cand < lrow) lrow = cand;
        }
    }

    if (lane < 32) {
        minp[((size_t)(m0 + wid*32 + lane) * SS + s) * 8 + blockIdx.x] = lrow;
    }
}

// ---------------------------------------------------------------------------
// Merge the 8 per-block minima per row -> final code.
// ---------------------------------------------------------------------------
__global__ __launch_bounds__(256) void reduce_min_v4(
    const unsigned long long* __restrict__ minp,   // [B*S][8]
    int* __restrict__ kfinal)
{
    int row = blockIdx.x * 256 + threadIdx.x;
    if (row >= B_ * SS) return;
    unsigned long long b1 = ~0ull;
    #pragma unroll
    for (int j = 0; j < 8; ++j) {
        unsigned long long v = minp[(size_t)row * 8 + j];
        if (v < b1) b1 = v;
    }
    kfinal[row] = (int)(b1 & 0xFFFFFFFFull);
}

// ---------------------------------------------------------------------------
// Gather quantized vectors, emit codes (as float), histogram counts.
// ---------------------------------------------------------------------------
__global__ __launch_bounds__(256) void gather_v4(
    const float* __restrict__ CB,
    const int* __restrict__ kfinal,
    float* __restrict__ quant,   // [B, 2048]
    float* __restrict__ codes,   // [B, S]
    unsigned* __restrict__ counts) // [S, K]
{
    const int b = blockIdx.x;
    const int tid = threadIdx.x;
    __shared__ int ks[SS];
    if (tid < SS) {
        int k = kfinal[(size_t)b * SS + tid];
        ks[tid] = k;
        codes[(size_t)b * SS + tid] = (float)k;
        atomicAdd(&counts[(size_t)tid * KCB + k], 1u);
    }
    __syncthreads();
    #pragma unroll
    for (int l = 0; l < 2; ++l) {
        int f  = tid + l * 256;
        int s  = f >> 6;
        int d4 = f & 63;
        float4 v = *(const float4*)(CB + ((size_t)s * KCB + ks[s]) * DD + d4 * 4);
        *(float4*)(quant + (size_t)b * ND + s * DD + d4 * 4) = v;
    }
}

// ---------------------------------------------------------------------------
__global__ __launch_bounds__(256) void perp_v4(
    const unsigned* __restrict__ counts, float* __restrict__ out)
{
    __shared__ float red[256];
    const int tid = threadIdx.x;
    const float inv = 1.0f / (float)B_;
    float sumP = 0.f;
    for (int s = 0; s < SS; ++s) {
        float h = 0.f;
        for (int k = tid; k < KCB; k += 256) {
            float p = (float)counts[(size_t)s * KCB + k] * inv;
            h += p * logf(p + 1e-10f);
        }
        red[tid] = h;
        __syncthreads();
        for (int w = 128; w; w >>= 1) {
            if (tid < w) red[tid] += red[tid + w];
            __syncthreads();
        }
        if (tid == 0) sumP += expf(-red[0]);
        __syncthreads();
    }
    if (tid == 0) out[0] = sumP / (float)SS;
}

// ---------------------------------------------------------------------------
extern "C" void kernel_launch(void* const* d_in, const int* in_sizes, int n_in,
                              void* d_out, int out_size, void* d_ws, size_t ws_size,
                              hipStream_t stream)
{
    const float* x     = (const float*)d_in[0];
    const float* enc_w = (const float*)d_in[1];
    const float* enc_b = (const float*)d_in[2];
    const float* cb    = (const float*)d_in[3];
    const float* dec_w = (const float*)d_in[4];
    const float* dec_b = (const float*)d_in[5];

    float* out0 = (float*)d_out;                       // x_recon (holds z temporarily)
    float* out1 = out0 + (size_t)B_ * ND;              // quantized_flat
    float* out2 = out1 + (size_t)B_ * ND;              // codes (as float)
    float* out3 = out2 + (size_t)B_ * SS;              // avg_perplexity scalar

    // workspace layout:
    //   minp   [B*S][8] u64 : 2 MB   (fully overwritten each call)
    //   counts [S*K] u32    : 256 KB (memset 0)
    //   kfinal [B*S] i32    : 128 KB
    //   zsq    [B*S] f32    : 128 KB
    char* wsb = (char*)d_ws;
    unsigned long long* minp = (unsigned long long*)wsb;
    size_t off = (size_t)B_ * SS * 8 * sizeof(unsigned long long);
    unsigned* counts = (unsigned*)(wsb + off);  off += (size_t)SS * KCB * 4;
    int*      kfinal = (int*)(wsb + off);       off += (size_t)B_ * SS * 4;
    float*    zsq    = (float*)(wsb + off);

    hipMemsetAsync(counts, 0, (size_t)SS * KCB * 4, stream);

    // 1. encoder GEMM: z -> out0 (temp)
    dim3 g1(ND / BN, B_ / BM);   // (16, 32)
    sgemm_nt_bias_v6<<<g1, 256, 0, stream>>>(x, enc_w, enc_b, out0, B_, ND, IN_DIM);

    // 2. per-(b,s) z_sq (the constant that drives the fp32 quantization)
    zsq_v4<<<(B_ * SS) / 4, 256, 0, stream>>>(out0, zsq);

    // 3. fused distance + argmin with reference-matching fp32 rounding
    dim3 g2(KCB / 1024, B_ / 128, SS);   // (8, 32, 8)
    dist_argmin_v11<<<g2, 256, 0, stream>>>(out0, cb, zsq, minp);

    // 4. merge per-block minima -> codes
    reduce_min_v4<<<(B_ * SS + 255) / 256, 256, 0, stream>>>(minp, kfinal);

    // 5. gather + codes + histogram
    gather_v4<<<B_, 256, 0, stream>>>(cb, kfinal, out1, out2, counts);

    // 6. decoder GEMM: x_recon -> out0 (overwrites z)
    sgemm_nt_bias_v6<<<g1, 256, 0, stream>>>(out1, dec_w, dec_b, out0, B_, IN_DIM, ND);

    // 7. perplexity scalar
    perp_v4<<<1, 256, 0, stream>>>(counts, out3);
}